// Round 12
// baseline (331.855 us; speedup 1.0000x reference)
//
#include <hip/hip_runtime.h>
#include <stdint.h>

typedef unsigned short u16;
typedef unsigned int   u32;
typedef int v4i __attribute__((ext_vector_type(4)));

static constexpr int Bd = 4096;   // batch
static constexpr int Kd = 2048;   // in-features (GEMM K)
static constexpr int Fd = 4096;   // out-features

// Workspace (bytes). yr aliases X1B+W1B (dead before GEMM writes).
// Max-scratch arrays live in the unused [48 MiB, 80 MiB) gap: written in K1/K2,
// read in K3, untouched by qwT/yr -> no aliasing.
static constexpr size_t OFF_QX   = 0;          // i8 [4096*2048]              (8 MB)
static constexpr size_t OFF_QWT  = 8388608;    // i8 [4096*2048] transposed   (8 MB)
static constexpr size_t OFF_X1B  = 16777216;   // u16[4096*2048] bf16         (16 MB)
static constexpr size_t OFF_W1B  = 33554432;   // u32[2048*2048] bf16 pairs   (16 MB)
static constexpr size_t OFF_YR   = 16777216;   // u16[4096*4096] aliases X1B/W1B (32 MB)
static constexpr size_t OFF_AUX  = 50331648;   // wmax[2048] u32 + xmax[256] u32
static constexpr size_t OFF_SCAL = 83886080;   // 2x u32 (max|X1|, max|W1| float bits)

// ---------------- FWHT helpers ----------------
__device__ __forceinline__ void fwht16(float* v) {
#pragma unroll
  for (int b = 1; b < 16; b <<= 1) {
#pragma unroll
    for (int i = 0; i < 16; ++i) {
      if (!(i & b)) { float a = v[i]; float c = v[i | b]; v[i] = a + c; v[i | b] = a - c; }
    }
  }
}
__device__ __forceinline__ void fwht64(float* v) {
#pragma unroll
  for (int b = 1; b < 64; b <<= 1) {
#pragma unroll
    for (int i = 0; i < 64; ++i) {
      if (!(i & b)) { float a = v[i]; float c = v[i | b]; v[i] = a + c; v[i | b] = a - c; }
    }
  }
}

// ---------------- bf16 pack/unpack ----------------
__device__ __forceinline__ void unpack2(u32 u, float& a, float& b) {
  a = __uint_as_float(u << 16);
  b = __uint_as_float(u & 0xffff0000u);
}
__device__ __forceinline__ float bf16_f32(u16 h) {
  return __uint_as_float(((u32)h) << 16);
}
__device__ __forceinline__ u16 bf16_rne(float f) {
  u32 x = __float_as_uint(f);
  return (u16)(((x + 0x7fffu + ((x >> 16) & 1u)) >> 16) & 0xffffu);
}
__device__ __forceinline__ u32 pack2(float a, float b) {
  u32 x = __float_as_uint(a), y = __float_as_uint(b);
  u32 lo = ((x + 0x7fffu + ((x >> 16) & 1u)) >> 16) & 0xffffu;
  u32 hi = (y + 0x7fffu + ((y >> 16) & 1u)) & 0xffff0000u;
  return lo | hi;
}

// ---- K1: fat_x -- full 4096-row x-rotation (both H64 stages) on an 8-col
// stripe via a 64 KB bf16 LDS tile. 512 threads: one column-group per thread
// per stage (no p-loop). Split out of R11's merged prep_xw so roww no longer
// inherits the 64 KB LDS allocation (R11 capped roww at 2 blocks/CU).
// Numerics bit-identical to R11's fat_x role.
__global__ __launch_bounds__(512) void fat_x(const float* __restrict__ x,
                                             u16* __restrict__ X1h,
                                             u32* __restrict__ xmax) {
  __shared__ u16 xl[4096 * 8];                 // 64 KB, swizzled
  __shared__ float redx[8];
  const int pid = blockIdx.x;                  // 0..255
  const int t = threadIdx.x;
  // XCD-aware col mapping: same-XCD blocks cover a contiguous 256-col region.
  const int C0 = (pid & 7) * 256 + (pid >> 3) * 8;
  const int c = t & 7, g = t >> 3;             // g 0..63
  float v[64];
  // stage A: H64 on contiguous 64-row groups, f32 in -> bf16 LDS
#pragma unroll
  for (int r = 0; r < 64; ++r)
    v[r] = x[(size_t)(64 * g + r) * 2048 + C0 + c];
  fwht64(v);
#pragma unroll
  for (int r = 0; r < 64; ++r)
    xl[512 * g + 8 * (r ^ (g & 7)) + c] = bf16_rne(v[r]);
  __syncthreads();
  // stage B: H64 on stride-64 rows, bf16 LDS -> bf16 global, + max
#pragma unroll
  for (int k = 0; k < 64; ++k)
    v[k] = bf16_f32(xl[512 * k + 8 * (g ^ (k & 7)) + c]);
  fwht64(v);
  float m = 0.f;
#pragma unroll
  for (int k = 0; k < 64; ++k) {
    X1h[(size_t)(g + 64 * k) * 2048 + C0 + c] = bf16_rne(v[k]);
    m = fmaxf(m, fabsf(v[k]));
  }
#pragma unroll
  for (int off = 32; off > 0; off >>= 1) m = fmaxf(m, __shfl_down(m, off));
  if ((t & 63) == 0) redx[t >> 6] = m;
  __syncthreads();
  if (t == 0) {
#pragma unroll
    for (int i = 1; i < 8; ++i) m = fmaxf(m, redx[i]);
    m = fmaxf(m, redx[0]);
    xmax[pid] = __float_as_uint(m);
  }
}

// ---- K2: w-path -- FWHT-4096 per row, f32 in -> bf16 out, block max -> wmax.
// Standalone again (16.9 KB LDS -> ~8 blocks/CU).
__global__ __launch_bounds__(256) void roww_fwht(const float* __restrict__ in,
                                                 u32* __restrict__ W1b,
                                                 u32* __restrict__ wmax) {
  __shared__ float s[4224];
  __shared__ float red[4];
  const int t = threadIdx.x;
  const int bx = blockIdx.x;                   // w row 0..2047
  const size_t rowoff = (size_t)bx * 4096;
  float v[16];
#pragma unroll
  for (int i = 0; i < 4; ++i) {
    int sl = t + 256 * i;
    float4 d = *(const float4*)(in + rowoff + sl * 4);
    int ep = sl * 4 + ((sl * 4) >> 5);
    s[ep + 0] = d.x; s[ep + 1] = d.y; s[ep + 2] = d.z; s[ep + 3] = d.w;
  }
  __syncthreads();
#pragma unroll
  for (int j = 0; j < 16; ++j) { int e = (j << 8) | t; v[j] = s[e + (e >> 5)]; }
  fwht16(v);
#pragma unroll
  for (int j = 0; j < 16; ++j) { int e = (j << 8) | t; s[e + (e >> 5)] = v[j]; }
  __syncthreads();
#pragma unroll
  for (int j = 0; j < 16; ++j) { int e = ((t >> 4) << 8) | (j << 4) | (t & 15); v[j] = s[e + (e >> 5)]; }
  fwht16(v);
#pragma unroll
  for (int j = 0; j < 16; ++j) { int e = ((t >> 4) << 8) | (j << 4) | (t & 15); s[e + (e >> 5)] = v[j]; }
  __syncthreads();
#pragma unroll
  for (int j = 0; j < 16; ++j) { int e = (t << 4) | j; v[j] = s[e + (e >> 5)]; }
  fwht16(v);
  uint4 o0, o1;
  o0.x = pack2(v[0], v[1]);   o0.y = pack2(v[2], v[3]);
  o0.z = pack2(v[4], v[5]);   o0.w = pack2(v[6], v[7]);
  o1.x = pack2(v[8], v[9]);   o1.y = pack2(v[10], v[11]);
  o1.z = pack2(v[12], v[13]); o1.w = pack2(v[14], v[15]);
  uint4* op = (uint4*)(W1b + (size_t)bx * 2048 + t * 8);
  op[0] = o0; op[1] = o1;
  float m = 0.f;
#pragma unroll
  for (int j = 0; j < 16; ++j) m = fmaxf(m, fabsf(v[j]));
#pragma unroll
  for (int off = 32; off > 0; off >>= 1) m = fmaxf(m, __shfl_down(m, off));
  if ((t & 63) == 0) red[t >> 6] = m;
  __syncthreads();
  if (t == 0) {
    m = fmaxf(fmaxf(red[0], red[1]), fmaxf(red[2], red[3]));
    wmax[bx] = __float_as_uint(m);
  }
}

// ---------------- Stochastic quantization ----------------
__device__ __forceinline__ float quant1(float X1, float nz, float s) {
  float xr = X1 * 0.015625f;         // /64, exact
  float xs = xr / s;
  float f  = floorf(xs);
  float q  = f + ((nz < (xs - f)) ? 1.0f : 0.0f);
  return fminf(fmaxf(q, -127.0f), 127.0f);
}
__device__ __forceinline__ u32 pk4(float a, float b, float c, float d) {
  return ((u32)(unsigned char)(char)(int)a)        |
         (((u32)(unsigned char)(char)(int)b) << 8) |
         (((u32)(unsigned char)(char)(int)c) << 16)|
         (((u32)(unsigned char)(char)(int)d) << 24);
}

// ---- K3: quant_x || quant_w_t merged; each role self-reduces its max array
// (exact fmax) and publishes scal for the gemm epilogue.
__global__ __launch_bounds__(256) void quant_xw(const uint4* __restrict__ X1b,
                                                const float4* __restrict__ nzx,
                                                uint2* __restrict__ qx,
                                                const u32* __restrict__ W1b,
                                                const float2* __restrict__ nzw,
                                                char* __restrict__ qwT,
                                                const u32* __restrict__ xmax,
                                                const u32* __restrict__ wmax,
                                                u32* __restrict__ scal) {
  __shared__ float tile[64][65];
  __shared__ float red[4];
  const int pid = blockIdx.x;
  const int t = threadIdx.x;
  if (pid < 4096) {
    // ---------------- quant_x role ----------------
    float xm = __uint_as_float(xmax[t]);       // 256 entries
#pragma unroll
    for (int off = 32; off > 0; off >>= 1) xm = fmaxf(xm, __shfl_down(xm, off));
    if ((t & 63) == 0) red[t >> 6] = xm;
    __syncthreads();
    xm = fmaxf(fmaxf(red[0], red[1]), fmaxf(red[2], red[3]));
    if (pid == 0 && t == 0) scal[0] = __float_as_uint(xm);
    float s = (xm * 0.015625f) / 127.0f;
    size_t g = (size_t)pid * 256 + t;
    uint4 xv = X1b[g];
    float4 na = nzx[2 * g], nb = nzx[2 * g + 1];
    float a, b, c, d, e, f, gg, h;
    unpack2(xv.x, a, b);  unpack2(xv.y, c, d);
    unpack2(xv.z, e, f);  unpack2(xv.w, gg, h);
    u32 lo = pk4(quant1(a, na.x, s), quant1(b, na.y, s), quant1(c, na.z, s), quant1(d, na.w, s));
    u32 hi = pk4(quant1(e, nb.x, s), quant1(f, nb.y, s), quant1(gg, nb.z, s), quant1(h, nb.w, s));
    qx[g] = make_uint2(lo, hi);
  } else {
    // ---------------- quant_w (transposed) role ----------------
    float wm = 0.f;
#pragma unroll
    for (int i = 0; i < 8; ++i) wm = fmaxf(wm, __uint_as_float(wmax[t + 256 * i]));
#pragma unroll
    for (int off = 32; off > 0; off >>= 1) wm = fmaxf(wm, __shfl_down(wm, off));
    if ((t & 63) == 0) red[t >> 6] = wm;
    __syncthreads();
    wm = fmaxf(fmaxf(red[0], red[1]), fmaxf(red[2], red[3]));
    if (pid == 4096 && t == 0) scal[1] = __float_as_uint(wm);
    float s = (wm * 0.015625f) / 127.0f;
    const int p = pid - 4096;
    const int k0 = (p & 31) * 64;   // over K=2048
    const int n0 = (p >> 5) * 64;   // over F=4096
#pragma unroll
    for (int i = 0; i < 8; ++i) {
      int idx = t + 256 * i;        // 0..2047 over (k, np)
      int k = idx >> 5, np = idx & 31;
      u32 u = W1b[(size_t)(k0 + k) * 2048 + (n0 >> 1) + np];
      float2 nv = nzw[(size_t)(k0 + k) * 2048 + (n0 >> 1) + np];
      float a, b; unpack2(u, a, b);
      tile[k][2 * np]     = quant1(a, nv.x, s);
      tile[k][2 * np + 1] = quant1(b, nv.y, s);
    }
    __syncthreads();
    const int kq = t & 15, nb = t >> 4;
#pragma unroll
    for (int i = 0; i < 4; ++i) {
      int n = nb + 16 * i;
      u32 pk = pk4(tile[4 * kq + 0][n], tile[4 * kq + 1][n],
                   tile[4 * kq + 2][n], tile[4 * kq + 3][n]);
      *(u32*)(qwT + (size_t)(n0 + n) * Kd + k0 + 4 * kq) = pk;
    }
  }
}

// ---------------- GEMM (i8 MFMA) + fused Rl/Cl output-rotation epilogue -------------
// 128^2 tile + 2-phase LDS double-buffer, GM=8 panel swizzle (R7/R9: 65 us;
// R6/R10 showed an environmental slow mode ~88 us with identical counters).
__device__ __forceinline__ void async16(const void* g, void* l) {
  __builtin_amdgcn_global_load_lds((__attribute__((address_space(1))) void*)(g),
                                   (__attribute__((address_space(3))) void*)(l),
                                   16, 0, 0);
}

__global__ __launch_bounds__(256) void gemm_i8(const char* __restrict__ A,   // [4096,2048] i8
                                               const char* __restrict__ Bt,  // [4096,2048] i8
                                               u16* __restrict__ C,          // [4096,4096] bf16
                                               const u32* __restrict__ scal) {
  __shared__ __align__(16) char As[2][128 * 128];
  __shared__ __align__(16) char Bs[2][128 * 128];
  const int t = threadIdx.x;
  const int w = t >> 6, l = t & 63;
  const int l15 = l & 15, quad = l >> 4;
  const int xorr = l15 & 7;
  // gm=8 panel swizzle for L2 locality (grid = 1024 1D)
  const int GM = 8, NN = 32, grp = GM * NN;
  int pid = blockIdx.x;
  int gid = pid / grp;
  int mm = gid * GM + (pid % GM);
  int nn = (pid % grp) / GM;
  const int m0 = mm * 128, n0 = nn * 128;
  const int mw = (w & 1) * 64, nw = (w >> 1) * 64;
  v4i acc[4][4] = {};

  // XOR source swizzle so LDS ds_read_b128 spreads over banks (0 conflicts)
  const int srow_lo = l >> 3;
  const int sbg = (l & 7) ^ ((l >> 3) & 7);

  // per-thread staging addresses (row/col within tile are kt-invariant)
  const int srow = (w * 4) * 8 + srow_lo;     // rows srow, srow+8, +16, +24
  const char* ga = A  + (size_t)(m0 + srow) * Kd + sbg * 16;
  const char* gb = Bt + (size_t)(n0 + srow) * Kd + sbg * 16;

  // prologue: stage K-tile 0 into buffer 0
#pragma unroll
  for (int i = 0; i < 4; ++i) {
    async16(ga + (size_t)(i * 8) * Kd, As[0] + (w * 4 + i) * 1024);
    async16(gb + (size_t)(i * 8) * Kd, Bs[0] + (w * 4 + i) * 1024);
  }
  __syncthreads();   // drains vmcnt(0): tile 0 resident

#pragma unroll 2
  for (int kt = 0; kt < 16; ++kt) {
    const char* curA = As[kt & 1];
    const char* curB = Bs[kt & 1];
    // issue next-tile staging into the alternate buffer (flies under compute)
    if (kt + 1 < 16) {
      char* nxtA = (char*)As[(kt + 1) & 1];
      char* nxtB = (char*)Bs[(kt + 1) & 1];
      const size_t kg = (size_t)(kt + 1) * 128;
#pragma unroll
      for (int i = 0; i < 4; ++i) {
        async16(ga + (size_t)(i * 8) * Kd + kg, nxtA + (w * 4 + i) * 1024);
        async16(gb + (size_t)(i * 8) * Kd + kg, nxtB + (w * 4 + i) * 1024);
      }
      __builtin_amdgcn_sched_barrier(0);   // pin: loads issued before compute
    }
#pragma unroll
    for (int kc = 0; kc < 2; ++kc) {
      v4i av[4], bv[4];
#pragma unroll
      for (int mi = 0; mi < 4; ++mi) {
        int row = mw + mi * 16 + l15;
        av[mi] = *(const v4i*)(curA + row * 128 + (((kc * 4 + quad) ^ xorr) * 16));
      }
#pragma unroll
      for (int ni = 0; ni < 4; ++ni) {
        int row = nw + ni * 16 + l15;
        bv[ni] = *(const v4i*)(curB + row * 128 + (((kc * 4 + quad) ^ xorr) * 16));
      }
#pragma unroll
      for (int mi = 0; mi < 4; ++mi)
#pragma unroll
        for (int ni = 0; ni < 4; ++ni)
          acc[mi][ni] = __builtin_amdgcn_mfma_i32_16x16x64_i8(av[mi], bv[ni], acc[mi][ni], 0, 0, 0);
    }
    // one barrier per tile: built-in vmcnt(0) waits only the residual latency
    // not covered by the compute above; also WAR-protects the buffer swap.
    __syncthreads();
  }
  float sx = (__uint_as_float(scal[0]) * 0.015625f) / 127.0f;
  float sw = (__uint_as_float(scal[1]) * 0.015625f) / 127.0f;
  float alpha = sx * sw * (1.0f / 4096.0f);

  // ---- fused epilogue: H64 over row-low bits (Rl) and col-low bits (Cl) ----
  float vals[64];
#pragma unroll
  for (int mi = 0; mi < 4; ++mi)
#pragma unroll
    for (int ni = 0; ni < 4; ++ni)
#pragma unroll
      for (int r = 0; r < 4; ++r)
        vals[mi * 16 + ni * 4 + r] = (float)acc[mi][ni][r] * alpha;
  fwht64(vals);
#pragma unroll
  for (int k = 0; k < 6; ++k) {
    const int mask = 1 << k;
    const int bit = (l >> k) & 1;
#pragma unroll
    for (int i = 0; i < 64; ++i) {
      float p = __shfl_xor(vals[i], mask, 64);
      vals[i] = bit ? (p - vals[i]) : (vals[i] + p);
    }
  }
#pragma unroll
  for (int mi = 0; mi < 4; ++mi)
#pragma unroll
    for (int ni = 0; ni < 4; ++ni)
#pragma unroll
      for (int r = 0; r < 4; ++r) {
        int row = m0 + mw + mi * 16 + quad * 4 + r;
        int col = n0 + nw + ni * 16 + l15;
        C[(size_t)row * Fd + col] = bf16_rne(vals[mi * 16 + ni * 4 + r]);
      }
}

// ---- Output pass Ch: H64 over col-high bits, per-row, bf16 in-place ----
// 2 rows/block (grid 2048, 16 KB LDS -> ~10 blocks/CU; waves 2-3 only help
// the load). Per-element FP order unchanged -> bit-identical.
__global__ __launch_bounds__(256) void colhigh_fwht(u16* __restrict__ yr) {
  __shared__ u16 sh[2 * 4096];   // 16 KB = 1024 uint4 -> 4 iters of 256 threads
  const int t = threadIdx.x;
  const size_t row0 = (size_t)blockIdx.x * 2;
  uint4* shv = (uint4*)sh;
  const uint4* g = (const uint4*)(yr + row0 * 4096);
#pragma unroll
  for (int i = 0; i < 4; ++i) shv[t + 256 * i] = g[t + 256 * i];
  __syncthreads();
  const int grp = t >> 6, cl = t & 63;
  if (grp < 2) {
    const u16* shr = sh + grp * 4096;
    float v[64];
#pragma unroll
    for (int ch = 0; ch < 64; ++ch)
      v[ch] = bf16_f32(shr[ch * 64 + cl]);
    fwht64(v);
    u16* out = yr + (row0 + grp) * 4096;
#pragma unroll
    for (int ch = 0; ch < 64; ++ch)
      out[ch * 64 + cl] = bf16_rne(v[ch]);
  }
}

// ---- Output pass Rh (LAST): H64 over stride-64 rows, +bias, f32 out ----
// 128-col chunks (grid 32x64, 17.4 KB LDS -> ~9 blocks/CU); uint4 loads.
__global__ __launch_bounds__(256) void rowhigh_last(const u16* __restrict__ in,
                                                    float* __restrict__ outf,
                                                    const float* __restrict__ bias) {
  __shared__ u16 tile[64 * 136];   // 64 rows x 128 cols, +8 u16 pad per row
  const int t = threadIdx.x;
  const int c0 = blockIdx.x * 128;          // col chunk base (grid.x = 32)
  const int base = blockIdx.y;              // 0..63
#pragma unroll
  for (int i = 0; i < 4; ++i) {
    int idx = t + 256 * i;                  // 0..1023
    int r = idx >> 4, u = idx & 15;         // 16 uint4 (256B) per row
    uint4 d = *(const uint4*)(in + (size_t)(base + r * 64) * 4096 + c0 + u * 8);
    *(uint4*)(&tile[r * 136 + u * 8]) = d;
  }
  __syncthreads();
  if (t < 128) {
    float v[64];
#pragma unroll
    for (int r = 0; r < 64; ++r) v[r] = bf16_f32(tile[r * 136 + t]);
    fwht64(v);
    const int c = c0 + t;
    float b0 = bias[c];
#pragma unroll
    for (int r = 0; r < 64; ++r)
      outf[(size_t)(base + r * 64) * 4096 + c] = v[r] + b0;
  }
}

// ---------------- Launch ----------------
extern "C" void kernel_launch(void* const* d_in, const int* in_sizes, int n_in,
                              void* d_out, int out_size, void* d_ws, size_t ws_size,
                              hipStream_t stream) {
  (void)in_sizes; (void)n_in; (void)out_size; (void)ws_size;
  const float* x       = (const float*)d_in[0];  // [4096,2048]
  const float* w       = (const float*)d_in[1];  // [2048,4096]
  const float* bias    = (const float*)d_in[2];  // [4096]
  const float* noise_x = (const float*)d_in[5];  // [4096,2048]
  const float* noise_w = (const float*)d_in[6];  // [2048,4096]
  char* ws = (char*)d_ws;
  char* qx   = (char*)(ws + OFF_QX);
  char* qwT  = (char*)(ws + OFF_QWT);
  u16*  X1h  = (u16*) (ws + OFF_X1B);
  u32*  W1b  = (u32*) (ws + OFF_W1B);
  u16*  yr   = (u16*) (ws + OFF_YR);
  u32*  wmax = (u32*) (ws + OFF_AUX);            // [2048]
  u32*  xmax = (u32*) (ws + OFF_AUX + 8192);     // [256]
  u32*  scal = (u32*) (ws + OFF_SCAL);
  float* out = (float*)d_out;

  // K1: full x rotation (both H64 stages, LDS-internal)
  fat_x<<<dim3(256), dim3(512), 0, stream>>>(x, X1h, xmax);
  // K2: w rotation (standalone again: 16.9 KB LDS -> ~8 blocks/CU)
  roww_fwht<<<dim3(2048), dim3(256), 0, stream>>>(w, W1b, wmax);
  // K3: stochastic int8 quantization of both operands (self-reduced maxima)
  quant_xw<<<dim3(4096 + 2048), dim3(256), 0, stream>>>(
      (const uint4*)X1h, (const float4*)noise_x, (uint2*)qx,
      W1b, (const float2*)noise_w, qwT, xmax, wmax, scal);
  // K4: core i8 GEMM (2-phase dbuf, GM=8) -> yr bf16 + fused Rl/Cl rotation
  gemm_i8<<<dim3((Bd / 128) * (Fd / 128)), dim3(256), 0, stream>>>(qx, qwT, yr, scal);
  // K5/K6: output stages: col-high, then row-high (+bias, f32)
  colhigh_fwht<<<dim3(Bd / 2), dim3(256), 0, stream>>>(yr);
  rowhigh_last<<<dim3(32, 64), dim3(256), 0, stream>>>(yr, out, bias);
}

// Round 13
// 326.693 us; speedup vs baseline: 1.0158x; 1.0158x over previous
//
#include <hip/hip_runtime.h>
#include <stdint.h>

typedef unsigned short u16;
typedef unsigned int   u32;
typedef int v4i __attribute__((ext_vector_type(4)));

static constexpr int Bd = 4096;   // batch
static constexpr int Kd = 2048;   // in-features (GEMM K)
static constexpr int Fd = 4096;   // out-features

// Workspace (bytes). yr aliases X1B+W1B (dead before GEMM writes).
// Max-scratch arrays live in the unused [48 MiB, 80 MiB) gap: written in K1,
// read in K2, untouched by qwT/yr -> no aliasing.
static constexpr size_t OFF_QX   = 0;          // i8 [4096*2048]              (8 MB)
static constexpr size_t OFF_QWT  = 8388608;    // i8 [4096*2048] transposed   (8 MB)
static constexpr size_t OFF_X1B  = 16777216;   // u16[4096*2048] bf16         (16 MB)
static constexpr size_t OFF_W1B  = 33554432;   // u32[2048*2048] bf16 pairs   (16 MB)
static constexpr size_t OFF_YR   = 16777216;   // u16[4096*4096] aliases X1B/W1B (32 MB)
static constexpr size_t OFF_AUX  = 50331648;   // wmax[2048] u32 + xmax[256] u32
static constexpr size_t OFF_SCAL = 83886080;   // 2x u32 (max|X1|, max|W1| float bits)

// ---------------- FWHT helpers ----------------
__device__ __forceinline__ void fwht16(float* v) {
#pragma unroll
  for (int b = 1; b < 16; b <<= 1) {
#pragma unroll
    for (int i = 0; i < 16; ++i) {
      if (!(i & b)) { float a = v[i]; float c = v[i | b]; v[i] = a + c; v[i | b] = a - c; }
    }
  }
}
__device__ __forceinline__ void fwht64(float* v) {
#pragma unroll
  for (int b = 1; b < 64; b <<= 1) {
#pragma unroll
    for (int i = 0; i < 64; ++i) {
      if (!(i & b)) { float a = v[i]; float c = v[i | b]; v[i] = a + c; v[i | b] = a - c; }
    }
  }
}

// ---------------- bf16 pack/unpack ----------------
__device__ __forceinline__ void unpack2(u32 u, float& a, float& b) {
  a = __uint_as_float(u << 16);
  b = __uint_as_float(u & 0xffff0000u);
}
__device__ __forceinline__ float bf16_f32(u16 h) {
  return __uint_as_float(((u32)h) << 16);
}
__device__ __forceinline__ u16 bf16_rne(float f) {
  u32 x = __float_as_uint(f);
  return (u16)(((x + 0x7fffu + ((x >> 16) & 1u)) >> 16) & 0xffffu);
}
__device__ __forceinline__ u32 pack2(float a, float b) {
  u32 x = __float_as_uint(a), y = __float_as_uint(b);
  u32 lo = ((x + 0x7fffu + ((x >> 16) & 1u)) >> 16) & 0xffffu;
  u32 hi = (y + 0x7fffu + ((y >> 16) & 1u)) & 0xffff0000u;
  return lo | hi;
}

// ---- K1: fat_x || roww_fwht merged (R11 config -- session best, 325.6 us) ----
// fat_x role (pid < 256): full 4096-row x-rotation on an 8-col stripe, both H64
// stages in one kernel via a 64 KB bf16 LDS tile (bf16 between stages = same
// numerics/FP-order as the old s1->s2 pair -> bit-identical). Per-block max ->
// xmax[pid]. LDS slot = 512g + 8*(r^(g&7)) + c: both stage-A and stage-B touch
// 32 distinct dwords per access -> <=2-way (free).
// roww role (pid >= 256): FWHT-4096 per w row; block max -> wmax.
// (R12 tried splitting these for roww occupancy: null/slightly worse.)
__global__ __launch_bounds__(256) void prep_xw(const float* __restrict__ x,
                                               u16* __restrict__ X1h,
                                               const float* __restrict__ w,
                                               u32* __restrict__ W1b,
                                               u32* __restrict__ wmax,
                                               u32* __restrict__ xmax) {
  __shared__ __align__(16) char ldsu[65568];   // union: fat_x 64K+16 | roww 16912
  const int pid = blockIdx.x;
  const int t = threadIdx.x;
  if (pid < 256) {
    // ---------------- fat_x role ----------------
    u16* xl = (u16*)ldsu;                      // [4096*8] bf16, swizzled
    float* redx = (float*)(ldsu + 65536);
    // XCD-aware col mapping: same-XCD blocks (pid%8 equal) cover a contiguous
    // 256-col region -> adjacent 64B lines of x stay in one XCD L2.
    const int C0 = (pid & 7) * 256 + (pid >> 3) * 8;
    const int c = t & 7;
    // stage A: H64 on contiguous 64-row groups, f32 in -> bf16 LDS
#pragma unroll
    for (int p = 0; p < 2; ++p) {
      const int g = (t >> 3) + 32 * p;         // 0..63
      float v[64];
#pragma unroll
      for (int r = 0; r < 64; ++r)
        v[r] = x[(size_t)(64 * g + r) * 2048 + C0 + c];
      fwht64(v);
#pragma unroll
      for (int r = 0; r < 64; ++r)
        xl[512 * g + 8 * (r ^ (g & 7)) + c] = bf16_rne(v[r]);
    }
    __syncthreads();
    // stage B: H64 on stride-64 rows, bf16 LDS -> bf16 global, + max
    float m = 0.f;
#pragma unroll
    for (int p = 0; p < 2; ++p) {
      const int b = (t >> 3) + 32 * p;         // 0..63
      float v[64];
#pragma unroll
      for (int k = 0; k < 64; ++k)
        v[k] = bf16_f32(xl[512 * k + 8 * ((b ^ (k & 7))) + c]);
      fwht64(v);
#pragma unroll
      for (int k = 0; k < 64; ++k) {
        X1h[(size_t)(b + 64 * k) * 2048 + C0 + c] = bf16_rne(v[k]);
        m = fmaxf(m, fabsf(v[k]));
      }
    }
#pragma unroll
    for (int off = 32; off > 0; off >>= 1) m = fmaxf(m, __shfl_down(m, off));
    if ((t & 63) == 0) redx[t >> 6] = m;
    __syncthreads();
    if (t == 0) {
      m = fmaxf(fmaxf(redx[0], redx[1]), fmaxf(redx[2], redx[3]));
      xmax[pid] = __float_as_uint(m);
    }
  } else {
    // ---------------- roww role ----------------
    float* s   = (float*)ldsu;                 // [4224]
    float* red = (float*)(ldsu + 16896);       // [4]
    const int bx = pid - 256;                  // w row 0..2047
    const size_t rowoff = (size_t)bx * 4096;
    float v[16];
#pragma unroll
    for (int i = 0; i < 4; ++i) {
      int sl = t + 256 * i;
      float4 d = *(const float4*)(w + rowoff + sl * 4);
      int ep = sl * 4 + ((sl * 4) >> 5);
      s[ep + 0] = d.x; s[ep + 1] = d.y; s[ep + 2] = d.z; s[ep + 3] = d.w;
    }
    __syncthreads();
#pragma unroll
    for (int j = 0; j < 16; ++j) { int e = (j << 8) | t; v[j] = s[e + (e >> 5)]; }
    fwht16(v);
#pragma unroll
    for (int j = 0; j < 16; ++j) { int e = (j << 8) | t; s[e + (e >> 5)] = v[j]; }
    __syncthreads();
#pragma unroll
    for (int j = 0; j < 16; ++j) { int e = ((t >> 4) << 8) | (j << 4) | (t & 15); v[j] = s[e + (e >> 5)]; }
    fwht16(v);
#pragma unroll
    for (int j = 0; j < 16; ++j) { int e = ((t >> 4) << 8) | (j << 4) | (t & 15); s[e + (e >> 5)] = v[j]; }
    __syncthreads();
#pragma unroll
    for (int j = 0; j < 16; ++j) { int e = (t << 4) | j; v[j] = s[e + (e >> 5)]; }
    fwht16(v);
    uint4 o0, o1;
    o0.x = pack2(v[0], v[1]);   o0.y = pack2(v[2], v[3]);
    o0.z = pack2(v[4], v[5]);   o0.w = pack2(v[6], v[7]);
    o1.x = pack2(v[8], v[9]);   o1.y = pack2(v[10], v[11]);
    o1.z = pack2(v[12], v[13]); o1.w = pack2(v[14], v[15]);
    uint4* op = (uint4*)(W1b + (size_t)bx * 2048 + t * 8);
    op[0] = o0; op[1] = o1;
    float m = 0.f;
#pragma unroll
    for (int j = 0; j < 16; ++j) m = fmaxf(m, fabsf(v[j]));
#pragma unroll
    for (int off = 32; off > 0; off >>= 1) m = fmaxf(m, __shfl_down(m, off));
    if ((t & 63) == 0) red[t >> 6] = m;
    __syncthreads();
    if (t == 0) {
      m = fmaxf(fmaxf(red[0], red[1]), fmaxf(red[2], red[3]));
      wmax[bx] = __float_as_uint(m);
    }
  }
}

// ---------------- Stochastic quantization ----------------
__device__ __forceinline__ float quant1(float X1, float nz, float s) {
  float xr = X1 * 0.015625f;         // /64, exact
  float xs = xr / s;
  float f  = floorf(xs);
  float q  = f + ((nz < (xs - f)) ? 1.0f : 0.0f);
  return fminf(fmaxf(q, -127.0f), 127.0f);
}
__device__ __forceinline__ u32 pk4(float a, float b, float c, float d) {
  return ((u32)(unsigned char)(char)(int)a)        |
         (((u32)(unsigned char)(char)(int)b) << 8) |
         (((u32)(unsigned char)(char)(int)c) << 16)|
         (((u32)(unsigned char)(char)(int)d) << 24);
}

// ---- K2: quant_x || quant_w_t merged; each role self-reduces its max array
// (exact fmax, same bits as the old atomicMax result) and publishes scal for
// the gemm epilogue (plain stores, stream-ordered before K3).
__global__ __launch_bounds__(256) void quant_xw(const uint4* __restrict__ X1b,
                                                const float4* __restrict__ nzx,
                                                uint2* __restrict__ qx,
                                                const u32* __restrict__ W1b,
                                                const float2* __restrict__ nzw,
                                                char* __restrict__ qwT,
                                                const u32* __restrict__ xmax,
                                                const u32* __restrict__ wmax,
                                                u32* __restrict__ scal) {
  __shared__ float tile[64][65];
  __shared__ float red[4];
  const int pid = blockIdx.x;
  const int t = threadIdx.x;
  if (pid < 4096) {
    // ---------------- quant_x role ----------------
    float xm = __uint_as_float(xmax[t]);       // 256 entries, t in 0..255
#pragma unroll
    for (int off = 32; off > 0; off >>= 1) xm = fmaxf(xm, __shfl_down(xm, off));
    if ((t & 63) == 0) red[t >> 6] = xm;
    __syncthreads();
    xm = fmaxf(fmaxf(red[0], red[1]), fmaxf(red[2], red[3]));
    if (pid == 0 && t == 0) scal[0] = __float_as_uint(xm);
    float s = (xm * 0.015625f) / 127.0f;
    size_t g = (size_t)pid * 256 + t;
    uint4 xv = X1b[g];
    float4 na = nzx[2 * g], nb = nzx[2 * g + 1];
    float a, b, c, d, e, f, gg, h;
    unpack2(xv.x, a, b);  unpack2(xv.y, c, d);
    unpack2(xv.z, e, f);  unpack2(xv.w, gg, h);
    u32 lo = pk4(quant1(a, na.x, s), quant1(b, na.y, s), quant1(c, na.z, s), quant1(d, na.w, s));
    u32 hi = pk4(quant1(e, nb.x, s), quant1(f, nb.y, s), quant1(gg, nb.z, s), quant1(h, nb.w, s));
    qx[g] = make_uint2(lo, hi);
  } else {
    // ---------------- quant_w (transposed) role ----------------
    float wm = 0.f;
#pragma unroll
    for (int i = 0; i < 8; ++i) wm = fmaxf(wm, __uint_as_float(wmax[t + 256 * i]));
#pragma unroll
    for (int off = 32; off > 0; off >>= 1) wm = fmaxf(wm, __shfl_down(wm, off));
    if ((t & 63) == 0) red[t >> 6] = wm;
    __syncthreads();
    wm = fmaxf(fmaxf(red[0], red[1]), fmaxf(red[2], red[3]));
    if (pid == 4096 && t == 0) scal[1] = __float_as_uint(wm);
    float s = (wm * 0.015625f) / 127.0f;
    const int p = pid - 4096;
    const int k0 = (p & 31) * 64;   // over K=2048
    const int n0 = (p >> 5) * 64;   // over F=4096
#pragma unroll
    for (int i = 0; i < 8; ++i) {
      int idx = t + 256 * i;        // 0..2047 over (k, np)
      int k = idx >> 5, np = idx & 31;
      u32 u = W1b[(size_t)(k0 + k) * 2048 + (n0 >> 1) + np];
      float2 nv = nzw[(size_t)(k0 + k) * 2048 + (n0 >> 1) + np];
      float a, b; unpack2(u, a, b);
      tile[k][2 * np]     = quant1(a, nv.x, s);
      tile[k][2 * np + 1] = quant1(b, nv.y, s);
    }
    __syncthreads();
    const int kq = t & 15, nb = t >> 4;
#pragma unroll
    for (int i = 0; i < 4; ++i) {
      int n = nb + 16 * i;
      u32 pk = pk4(tile[4 * kq + 0][n], tile[4 * kq + 1][n],
                   tile[4 * kq + 2][n], tile[4 * kq + 3][n]);
      *(u32*)(qwT + (size_t)(n0 + n) * Kd + k0 + 4 * kq) = pk;
    }
  }
}

// ---------------- GEMM (i8 MFMA) + fused Rl/Cl output-rotation epilogue -------------
// 128^2 tile + 2-phase LDS double-buffer, GM=8 panel swizzle (R7/R9/R11/R12:
// 65 us fast-mode; R6/R10 showed an environmental slow mode ~88 us with
// identical counters). Structure ceiling for this class; 8-phase ports
// regressed 3x (R1-R3).
__device__ __forceinline__ void async16(const void* g, void* l) {
  __builtin_amdgcn_global_load_lds((__attribute__((address_space(1))) void*)(g),
                                   (__attribute__((address_space(3))) void*)(l),
                                   16, 0, 0);
}

__global__ __launch_bounds__(256) void gemm_i8(const char* __restrict__ A,   // [4096,2048] i8
                                               const char* __restrict__ Bt,  // [4096,2048] i8
                                               u16* __restrict__ C,          // [4096,4096] bf16
                                               const u32* __restrict__ scal) {
  __shared__ __align__(16) char As[2][128 * 128];
  __shared__ __align__(16) char Bs[2][128 * 128];
  const int t = threadIdx.x;
  const int w = t >> 6, l = t & 63;
  const int l15 = l & 15, quad = l >> 4;
  const int xorr = l15 & 7;
  // gm=8 panel swizzle for L2 locality (grid = 1024 1D)
  const int GM = 8, NN = 32, grp = GM * NN;
  int pid = blockIdx.x;
  int gid = pid / grp;
  int mm = gid * GM + (pid % GM);
  int nn = (pid % grp) / GM;
  const int m0 = mm * 128, n0 = nn * 128;
  const int mw = (w & 1) * 64, nw = (w >> 1) * 64;
  v4i acc[4][4] = {};

  // XOR source swizzle so LDS ds_read_b128 spreads over banks (0 conflicts)
  const int srow_lo = l >> 3;
  const int sbg = (l & 7) ^ ((l >> 3) & 7);

  // per-thread staging addresses (row/col within tile are kt-invariant)
  const int srow = (w * 4) * 8 + srow_lo;     // rows srow, srow+8, +16, +24
  const char* ga = A  + (size_t)(m0 + srow) * Kd + sbg * 16;
  const char* gb = Bt + (size_t)(n0 + srow) * Kd + sbg * 16;

  // prologue: stage K-tile 0 into buffer 0
#pragma unroll
  for (int i = 0; i < 4; ++i) {
    async16(ga + (size_t)(i * 8) * Kd, As[0] + (w * 4 + i) * 1024);
    async16(gb + (size_t)(i * 8) * Kd, Bs[0] + (w * 4 + i) * 1024);
  }
  __syncthreads();   // drains vmcnt(0): tile 0 resident

#pragma unroll 2
  for (int kt = 0; kt < 16; ++kt) {
    const char* curA = As[kt & 1];
    const char* curB = Bs[kt & 1];
    // issue next-tile staging into the alternate buffer (flies under compute)
    if (kt + 1 < 16) {
      char* nxtA = (char*)As[(kt + 1) & 1];
      char* nxtB = (char*)Bs[(kt + 1) & 1];
      const size_t kg = (size_t)(kt + 1) * 128;
#pragma unroll
      for (int i = 0; i < 4; ++i) {
        async16(ga + (size_t)(i * 8) * Kd + kg, nxtA + (w * 4 + i) * 1024);
        async16(gb + (size_t)(i * 8) * Kd + kg, nxtB + (w * 4 + i) * 1024);
      }
      __builtin_amdgcn_sched_barrier(0);   // pin: loads issued before compute
    }
#pragma unroll
    for (int kc = 0; kc < 2; ++kc) {
      v4i av[4], bv[4];
#pragma unroll
      for (int mi = 0; mi < 4; ++mi) {
        int row = mw + mi * 16 + l15;
        av[mi] = *(const v4i*)(curA + row * 128 + (((kc * 4 + quad) ^ xorr) * 16));
      }
#pragma unroll
      for (int ni = 0; ni < 4; ++ni) {
        int row = nw + ni * 16 + l15;
        bv[ni] = *(const v4i*)(curB + row * 128 + (((kc * 4 + quad) ^ xorr) * 16));
      }
#pragma unroll
      for (int mi = 0; mi < 4; ++mi)
#pragma unroll
        for (int ni = 0; ni < 4; ++ni)
          acc[mi][ni] = __builtin_amdgcn_mfma_i32_16x16x64_i8(av[mi], bv[ni], acc[mi][ni], 0, 0, 0);
    }
    // one barrier per tile: built-in vmcnt(0) waits only the residual latency
    // not covered by the compute above; also WAR-protects the buffer swap.
    __syncthreads();
  }
  float sx = (__uint_as_float(scal[0]) * 0.015625f) / 127.0f;
  float sw = (__uint_as_float(scal[1]) * 0.015625f) / 127.0f;
  float alpha = sx * sw * (1.0f / 4096.0f);

  // ---- fused epilogue: H64 over row-low bits (Rl) and col-low bits (Cl) ----
  float vals[64];
#pragma unroll
  for (int mi = 0; mi < 4; ++mi)
#pragma unroll
    for (int ni = 0; ni < 4; ++ni)
#pragma unroll
      for (int r = 0; r < 4; ++r)
        vals[mi * 16 + ni * 4 + r] = (float)acc[mi][ni][r] * alpha;
  fwht64(vals);
#pragma unroll
  for (int k = 0; k < 6; ++k) {
    const int mask = 1 << k;
    const int bit = (l >> k) & 1;
#pragma unroll
    for (int i = 0; i < 64; ++i) {
      float p = __shfl_xor(vals[i], mask, 64);
      vals[i] = bit ? (p - vals[i]) : (vals[i] + p);
    }
  }
#pragma unroll
  for (int mi = 0; mi < 4; ++mi)
#pragma unroll
    for (int ni = 0; ni < 4; ++ni)
#pragma unroll
      for (int r = 0; r < 4; ++r) {
        int row = m0 + mw + mi * 16 + quad * 4 + r;
        int col = n0 + nw + ni * 16 + l15;
        C[(size_t)row * Fd + col] = bf16_rne(vals[mi * 16 + ni * 4 + r]);
      }
}

// ---------------- Output pass Ch: H64 over col-high bits, per-row, bf16 in-place ----
__global__ __launch_bounds__(256) void colhigh_fwht(u16* __restrict__ yr) {
  __shared__ u16 sh[4 * 4096];   // 32768 B = 2048 uint4 -> 8 iters of 256 threads
  const int t = threadIdx.x;
  const size_t row0 = (size_t)blockIdx.x * 4;
  uint4* shv = (uint4*)sh;
  const uint4* g = (const uint4*)(yr + row0 * 4096);
#pragma unroll
  for (int i = 0; i < 8; ++i) shv[t + 256 * i] = g[t + 256 * i];
  __syncthreads();
  const int grp = t >> 6, cl = t & 63;
  const u16* shr = sh + grp * 4096;
  float v[64];
#pragma unroll
  for (int ch = 0; ch < 64; ++ch)
    v[ch] = __uint_as_float(((u32)shr[ch * 64 + cl]) << 16);
  fwht64(v);
  __syncthreads();
  u16* shw = sh + grp * 4096;
#pragma unroll
  for (int ch = 0; ch < 64; ++ch)
    shw[ch * 64 + cl] = bf16_rne(v[ch]);
  __syncthreads();
  uint4* go = (uint4*)(yr + row0 * 4096);
#pragma unroll
  for (int i = 0; i < 8; ++i) go[t + 256 * i] = shv[t + 256 * i];
}

// ---- Output pass Rh (LAST): H64 over stride-64 rows, +bias, f32 out ----
// LDS-staged loads (G13): uint4 global reads instead of scalar u16.
__global__ __launch_bounds__(256) void rowhigh_last(const u16* __restrict__ in,
                                                    float* __restrict__ outf,
                                                    const float* __restrict__ bias) {
  __shared__ u16 tile[64 * 264];   // 64 rows x 256 cols, +8 u16 pad per row
  const int t = threadIdx.x;
  const int c0 = blockIdx.x * 256;          // col chunk base (grid.x = 16)
  const int base = blockIdx.y;              // 0..63
#pragma unroll
  for (int i = 0; i < 8; ++i) {
    int idx = t + 256 * i;                  // 0..2047
    int r = idx >> 5, u = idx & 31;
    uint4 d = *(const uint4*)(in + (size_t)(base + r * 64) * 4096 + c0 + u * 8);
    *(uint4*)(&tile[r * 264 + u * 8]) = d;
  }
  __syncthreads();
  float v[64];
#pragma unroll
  for (int r = 0; r < 64; ++r) v[r] = bf16_f32(tile[r * 264 + t]);
  fwht64(v);
  const int c = c0 + t;
  float b0 = bias[c];
#pragma unroll
  for (int r = 0; r < 64; ++r)
    outf[(size_t)(base + r * 64) * 4096 + c] = v[r] + b0;
}

// ---------------- Launch ----------------
extern "C" void kernel_launch(void* const* d_in, const int* in_sizes, int n_in,
                              void* d_out, int out_size, void* d_ws, size_t ws_size,
                              hipStream_t stream) {
  (void)in_sizes; (void)n_in; (void)out_size; (void)ws_size;
  const float* x       = (const float*)d_in[0];  // [4096,2048]
  const float* w       = (const float*)d_in[1];  // [2048,4096]
  const float* bias    = (const float*)d_in[2];  // [4096]
  const float* noise_x = (const float*)d_in[5];  // [4096,2048]
  const float* noise_w = (const float*)d_in[6];  // [2048,4096]
  char* ws = (char*)d_ws;
  char* qx   = (char*)(ws + OFF_QX);
  char* qwT  = (char*)(ws + OFF_QWT);
  u16*  X1h  = (u16*) (ws + OFF_X1B);
  u32*  W1b  = (u32*) (ws + OFF_W1B);
  u16*  yr   = (u16*) (ws + OFF_YR);
  u32*  wmax = (u32*) (ws + OFF_AUX);            // [2048]
  u32*  xmax = (u32*) (ws + OFF_AUX + 8192);     // [256]
  u32*  scal = (u32*) (ws + OFF_SCAL);
  float* out = (float*)d_out;

  // K1: full x rotation (both H64 stages, LDS-internal) || w rotation
  prep_xw<<<dim3(256 + 2048), dim3(256), 0, stream>>>(x, X1h, w, W1b, wmax, xmax);
  // K2: stochastic int8 quantization of both operands (self-reduced maxima)
  quant_xw<<<dim3(4096 + 2048), dim3(256), 0, stream>>>(
      (const uint4*)X1h, (const float4*)noise_x, (uint2*)qx,
      W1b, (const float2*)noise_w, qwT, xmax, wmax, scal);
  // K3: core i8 GEMM (2-phase dbuf, GM=8) -> yr bf16 + fused Rl/Cl rotation
  gemm_i8<<<dim3((Bd / 128) * (Fd / 128)), dim3(256), 0, stream>>>(qx, qwT, yr, scal);
  // K4/K5: output stages: col-high, then row-high (+bias, f32)
  colhigh_fwht<<<dim3(Bd / 4), dim3(256), 0, stream>>>(yr);
  rowhigh_last<<<dim3(16, 64), dim3(256), 0, stream>>>(yr, out, bias);
}